// Round 2
// baseline (167.874 us; speedup 1.0000x reference)
//
#include <hip/hip_runtime.h>
#include <math.h>

#define KG_B   16384
#define KG_D   128
#define KG_NR  24
#define KG_G   8                          // batch elements per wave
#define KG_BPAD (KG_B + KG_NR * KG_G)     // 16576 padded slots
#define KG_NGROUPS (KG_BPAD / KG_G)       // 2072 groups

// ws layout (ints): [0,32) cnt | [32,64) cur | [64,96) pbase | [96,96+BPAD) perm
// then floats: terms[BPAD]
#define WS_CNT   0
#define WS_CUR   32
#define WS_PBASE 64
#define WS_PERM  96
#define WS_TERMS (96 + KG_BPAD)

// ---- K0: init perm=-1, zero counters ----
__global__ __launch_bounds__(256) void kg_init(int* wsi) {
    const int i = blockIdx.x * 256 + threadIdx.x;
    if (i < KG_BPAD) wsi[WS_PERM + i] = -1;
    if (i < 64) wsi[WS_CNT + i] = 0;   // zeroes cnt[32] and cur[32]
}

// ---- K1: histogram over relations ----
__global__ __launch_bounds__(256) void kg_hist(const int* __restrict__ r, int* wsi) {
    const int b = blockIdx.x * 256 + threadIdx.x;
    if (b < KG_B) atomicAdd(&wsi[WS_CNT + r[b]], 1);
}

// ---- K2: padded exclusive scan over 24 bins (single thread) ----
__global__ void kg_scan(int* wsi) {
    int running = 0;
    for (int k = 0; k < KG_NR; ++k) {
        wsi[WS_PBASE + k] = running;
        running += (wsi[WS_CNT + k] + KG_G - 1) & ~(KG_G - 1);
    }
}

// ---- K3: scatter into padded relation segments ----
__global__ __launch_bounds__(256) void kg_scatter(const int* __restrict__ r, int* wsi) {
    const int b = blockIdx.x * 256 + threadIdx.x;
    if (b < KG_B) {
        const int k = r[b];
        const int pos = wsi[WS_PBASE + k] + atomicAdd(&wsi[WS_CUR + k], 1);
        wsi[WS_PERM + pos] = b;
    }
}

// ---- K4: main. One wave per group of 8 same-relation elements. ----
__global__ __launch_bounds__(64) void kg_main(
    const float* __restrict__ ent,   // [300000,128]
    const float* __restrict__ rel,   // [24,128]
    const float* __restrict__ M,     // [24,128,128]
    const int*   __restrict__ h,
    const int*   __restrict__ r,
    const int*   __restrict__ pt,
    const int*   __restrict__ nt,
    const int*   __restrict__ perm,
    float*       __restrict__ terms)
{
    const int group = blockIdx.x;
    const int lane  = threadIdx.x;
    const int slot0 = group * KG_G;

    __shared__ float4 sv[KG_G][KG_D];    // .x=vh .y=vp .z=vn per (g,e)

    int pg[KG_G];
#pragma unroll
    for (int g = 0; g < KG_G; ++g) pg[g] = perm[slot0 + g];

    int rb = -1;
#pragma unroll
    for (int g = 0; g < KG_G; ++g)
        if (rb < 0 && pg[g] >= 0) rb = r[pg[g]];

    if (rb < 0) {                        // fully-padded trailing group
        if (lane < KG_G) terms[slot0 + lane] = 0.f;
        return;
    }

    // relation embedding stays in registers (shared by the whole group)
    const float2 rrv = *(const float2*)(rel + (size_t)rb * KG_D + 2 * lane);

    // stage gathered vectors: sv[g][e] = {h, pos, neg} value at dim e
#pragma unroll
    for (int g = 0; g < KG_G; ++g) {
        const int bb = pg[g] >= 0 ? pg[g] : 0;     // safe index for padding
        const int ih = h[bb];
        const int ip = pt[bb];
        const int it = nt[bb];
        const float2 vh = *(const float2*)(ent + (size_t)ih * KG_D + 2 * lane);
        const float2 vp = *(const float2*)(ent + (size_t)ip * KG_D + 2 * lane);
        const float2 vn = *(const float2*)(ent + (size_t)it * KG_D + 2 * lane);
        sv[g][2 * lane]     = make_float4(vh.x, vp.x, vn.x, 0.f);
        sv[g][2 * lane + 1] = make_float4(vh.y, vp.y, vn.y, 0.f);
    }
    __syncthreads();

    const float* __restrict__ Wr = M + (size_t)rb * KG_D * KG_D;

    float ah0[KG_G], ah1[KG_G], ap0[KG_G], ap1[KG_G], an0[KG_G], an1[KG_G];
#pragma unroll
    for (int g = 0; g < KG_G; ++g) {
        ah0[g] = ah1[g] = ap0[g] = ap1[g] = an0[g] = an1[g] = 0.f;
    }

#pragma unroll 4
    for (int e = 0; e < KG_D; ++e) {
        const float2 w = *(const float2*)(Wr + (size_t)e * KG_D + 2 * lane);
#pragma unroll
        for (int g = 0; g < KG_G; ++g) {
            const float4 v = sv[g][e];   // broadcast ds_read_b128
            ah0[g] = fmaf(v.x, w.x, ah0[g]); ah1[g] = fmaf(v.x, w.y, ah1[g]);
            ap0[g] = fmaf(v.y, w.x, ap0[g]); ap1[g] = fmaf(v.y, w.y, ap1[g]);
            an0[g] = fmaf(v.z, w.x, an0[g]); an1[g] = fmaf(v.z, w.y, an1[g]);
        }
    }

#pragma unroll
    for (int g = 0; g < KG_G; ++g) {
        const float dp0 = ah0[g] + rrv.x - ap0[g];
        const float dp1 = ah1[g] + rrv.y - ap1[g];
        const float dn0 = ah0[g] + rrv.x - an0[g];
        const float dn1 = ah1[g] + rrv.y - an1[g];

        float ps  = dp0 * dp0 + dp1 * dp1;
        float ns  = dn0 * dn0 + dn1 * dn1;
        float ssq = ah0[g] * ah0[g] + ah1[g] * ah1[g]
                  + ap0[g] * ap0[g] + ap1[g] * ap1[g]
                  + an0[g] * an0[g] + an1[g] * an1[g]
                  + rrv.x * rrv.x + rrv.y * rrv.y;

        for (int off = 32; off > 0; off >>= 1) {
            ps  += __shfl_down(ps, off);
            ns  += __shfl_down(ns, off);
            ssq += __shfl_down(ssq, off);
        }

        if (lane == 0) {
            float term = 0.f;
            if (pg[g] >= 0) {
                const float x = ps - ns;                      // pos - neg
                term = fmaxf(x, 0.f) + log1pf(expf(-fabsf(x)))  // softplus
                     + 1e-5f * 0.5f * ssq;
            }
            terms[slot0 + g] = term;
        }
    }
}

// ---- K5: deterministic single-block reduction ----
__global__ __launch_bounds__(256) void kg_reduce(const float* __restrict__ terms,
                                                 float* __restrict__ out) {
    __shared__ float s[256];
    const int t = threadIdx.x;
    float acc = 0.f;
    for (int i = t; i < KG_BPAD; i += 256) acc += terms[i];
    s[t] = acc;
    __syncthreads();
    for (int off = 128; off > 0; off >>= 1) {
        if (t < off) s[t] += s[t + off];
        __syncthreads();
    }
    if (t == 0) out[0] = s[0] * (1.0f / (float)KG_B);
}

extern "C" void kernel_launch(void* const* d_in, const int* in_sizes, int n_in,
                              void* d_out, int out_size, void* d_ws, size_t ws_size,
                              hipStream_t stream) {
    const float* ent = (const float*)d_in[0];
    const float* rel = (const float*)d_in[1];
    const float* M   = (const float*)d_in[2];
    const int*   h   = (const int*)d_in[3];
    const int*   r   = (const int*)d_in[4];
    const int*   pt  = (const int*)d_in[5];
    const int*   nt  = (const int*)d_in[6];

    int*   wsi   = (int*)d_ws;
    float* terms = (float*)d_ws + WS_TERMS;
    float* out   = (float*)d_out;

    const int nb256 = (KG_BPAD + 255) / 256;   // 65 — covers B and BPAD strides

    kg_init   <<<nb256, 256, 0, stream>>>(wsi);
    kg_hist   <<<(KG_B + 255) / 256, 256, 0, stream>>>(r, wsi);
    kg_scan   <<<1, 1, 0, stream>>>(wsi);
    kg_scatter<<<(KG_B + 255) / 256, 256, 0, stream>>>(r, wsi);
    kg_main   <<<KG_NGROUPS, 64, 0, stream>>>(ent, rel, M, h, r, pt, nt,
                                              wsi + WS_PERM, terms);
    kg_reduce <<<1, 256, 0, stream>>>(terms, out);
}

// Round 3
// 95.554 us; speedup vs baseline: 1.7569x; 1.7569x over previous
//
#include <hip/hip_runtime.h>
#include <math.h>

#define KG_B    16384
#define KG_D    128
#define KG_NR   24
#define KG_GE   64                         // elements per group (= wave lanes)
#define KG_BPAD (KG_B + KG_NR * KG_GE)     // 17920 worst-case padded slots
#define KG_NGRP (KG_BPAD / KG_GE)          // 280 groups
#define KG_NBLK (KG_NGRP * 2)              // 560 blocks (2 col-halves)

// ws layout: int perm[KG_BPAD] | float pbuf[KG_BPAD*6] (ps,ns,sq × 2 halves)

// ---------------- K1: single-block relation sort (LDS counters) ----------
__global__ __launch_bounds__(1024) void kg_sort(const int* __restrict__ r,
                                                int* __restrict__ perm) {
    __shared__ int cntw[16][25];     // per-wave counters (padded rows)
    __shared__ int basew[16][25];
    __shared__ int pbase_s[24];
    __shared__ int cnt_tot[24];
    __shared__ int total_s;

    const int t = threadIdx.x;
    const int w = t >> 6;

    int* cz = &cntw[0][0];
    for (int i = t; i < 16 * 25; i += 1024) cz[i] = 0;
    __syncthreads();

    int kt[16];
#pragma unroll
    for (int j = 0; j < 16; ++j) kt[j] = r[j * 1024 + t];
#pragma unroll
    for (int j = 0; j < 16; ++j) atomicAdd(&cntw[w][kt[j]], 1);
    __syncthreads();

    if (t < 24) {                     // scan the 16 wave-counts per relation
        int s = 0;
        for (int w2 = 0; w2 < 16; ++w2) { basew[w2][t] = s; s += cntw[w2][t]; }
        cnt_tot[t] = s;
    }
    __syncthreads();
    if (t == 0) {                     // padded exclusive scan over relations
        int run = 0;
        for (int k = 0; k < 24; ++k) {
            pbase_s[k] = run;
            run += (cnt_tot[k] + (KG_GE - 1)) & ~(KG_GE - 1);
        }
        total_s = run;
    }
    __syncthreads();
    if (t < 24)
        for (int w2 = 0; w2 < 16; ++w2) basew[w2][t] += pbase_s[t];
    for (int i = t; i < 16 * 25; i += 1024) cz[i] = 0;   // reuse cntw as cur
    __syncthreads();

#pragma unroll
    for (int j = 0; j < 16; ++j) {
        const int k = kt[j];
        const int pos = basew[w][k] + atomicAdd(&cntw[w][k], 1);
        perm[pos] = j * 1024 + t;
    }
    __syncthreads();

    if (t < 24) {                     // pad gaps inside each segment
        const int e0 = pbase_s[t] + cnt_tot[t];
        const int e1 = pbase_s[t] + ((cnt_tot[t] + (KG_GE - 1)) & ~(KG_GE - 1));
        for (int p = e0; p < e1; ++p) perm[p] = -1;
    }
    for (int i = total_s + t; i < KG_BPAD; i += 1024) perm[i] = -1;
}

// ---------------- K2: main. lane = element, W broadcast via SGPRs. -------
__global__ __launch_bounds__(256) void kg_main(
    const float* __restrict__ ent,   // [300128,128]
    const float* __restrict__ rel,   // [24,128]
    const float* __restrict__ M,     // [24,128,128]
    const int*   __restrict__ h,
    const int*   __restrict__ r,
    const int*   __restrict__ pt,
    const int*   __restrict__ nt,
    const int*   __restrict__ perm,
    float*       __restrict__ pbuf)
{
    __shared__ uint2 sv[KG_GE][KG_D];   // 64 KB: packed bf16 {h|p, n} swizzled

    const int tid   = threadIdx.x;
    const int lane  = tid & 63;
    const int w     = __builtin_amdgcn_readfirstlane(tid >> 6);  // wave id (uniform)
    const int group = blockIdx.x >> 1;
    const int ch    = blockIdx.x & 1;
    const int j0    = ch * 64 + w * 16;     // this wave's 16-col chunk
    const int slot0 = group * KG_GE;

    const int p0 = perm[slot0];
    if (p0 < 0) return;                     // fully-padded trailing group
    const int rb = __builtin_amdgcn_readfirstlane(r[p0]);

    const int pidx = perm[slot0 + lane];

    // ---- stage 64 elements: bf16-pack {h,p,n}, XOR-swizzled columns ----
    const int gg0 = w * 16;
#pragma unroll 4
    for (int q = 0; q < 16; ++q) {
        const int gg = gg0 + q;
        int bb = __builtin_amdgcn_readlane(pidx, gg);   // SGPR, uniform
        bb = bb < 0 ? 0 : bb;
        const int ih = h[bb], ip = pt[bb], in_ = nt[bb];
        const float2 hv = *(const float2*)(ent + (size_t)ih * KG_D + 2 * lane);
        const float2 pv = *(const float2*)(ent + (size_t)ip * KG_D + 2 * lane);
        const float2 nv = *(const float2*)(ent + (size_t)in_ * KG_D + 2 * lane);
        const int c    = gg & 15;
        const unsigned hx = (__float_as_uint(hv.x) + 0x8000u) & 0xffff0000u;
        const unsigned px = (__float_as_uint(pv.x) + 0x8000u) >> 16;
        const unsigned nx = (__float_as_uint(nv.x) + 0x8000u) & 0xffff0000u;
        const unsigned hy = (__float_as_uint(hv.y) + 0x8000u) & 0xffff0000u;
        const unsigned py = (__float_as_uint(pv.y) + 0x8000u) >> 16;
        const unsigned ny = (__float_as_uint(nv.y) + 0x8000u) & 0xffff0000u;
        sv[gg][(2 * lane)     ^ c] = make_uint2(hx | px, nx);
        sv[gg][(2 * lane + 1) ^ c] = make_uint2(hy | py, ny);
    }
    __syncthreads();

    // ---- main loop: per e, 16 uniform W floats (SGPR) × 3 vecs × 16 cols ----
    float ah[16], ap[16], an[16];
#pragma unroll
    for (int c = 0; c < 16; ++c) { ah[c] = 0.f; ap[c] = 0.f; an[c] = 0.f; }

    const float* __restrict__ Wr = M + ((size_t)rb << 14) + j0;
    const uint2* __restrict__ svr = sv[lane];
    const int g15 = lane & 15;

#pragma unroll 2
    for (int e = 0; e < KG_D; ++e) {
        const uint2 pv = svr[e ^ g15];
        const float4 w0 = *(const float4*)(Wr + (size_t)e * KG_D);
        const float4 w1 = *(const float4*)(Wr + (size_t)e * KG_D + 4);
        const float4 w2 = *(const float4*)(Wr + (size_t)e * KG_D + 8);
        const float4 w3 = *(const float4*)(Wr + (size_t)e * KG_D + 12);
        const float vh = __uint_as_float(pv.x & 0xffff0000u);
        const float vp = __uint_as_float(pv.x << 16);
        const float vn = __uint_as_float(pv.y);
        const float wv[16] = { w0.x, w0.y, w0.z, w0.w, w1.x, w1.y, w1.z, w1.w,
                               w2.x, w2.y, w2.z, w2.w, w3.x, w3.y, w3.z, w3.w };
#pragma unroll
        for (int c = 0; c < 16; ++c) {
            ah[c] = fmaf(vh, wv[c], ah[c]);
            ap[c] = fmaf(vp, wv[c], ap[c]);
            an[c] = fmaf(vn, wv[c], an[c]);
        }
    }

    // ---- per-lane partials over this wave's 16 cols ----
    const float* __restrict__ rrow = rel + rb * KG_D + j0;   // uniform
    float ps = 0.f, ns = 0.f, sq = 0.f;
#pragma unroll
    for (int c = 0; c < 16; ++c) {
        const float rcv = rrow[c];
        const float s  = ah[c] + rcv;
        const float dp = s - ap[c];
        const float dn = s - an[c];
        ps += dp * dp;
        ns += dn * dn;
        sq += ah[c] * ah[c] + ap[c] * ap[c] + an[c] * an[c] + rcv * rcv;
    }

    __syncthreads();                       // sv reads done; reuse LDS
    float* part = (float*)&sv[0][0];
    part[tid]       = ps;
    part[256 + tid] = ns;
    part[512 + tid] = sq;
    __syncthreads();

    if (tid < KG_GE) {
        float P = 0.f, N = 0.f, S = 0.f;
#pragma unroll
        for (int w2 = 0; w2 < 4; ++w2) {
            P += part[w2 * 64 + tid];
            N += part[256 + w2 * 64 + tid];
            S += part[512 + w2 * 64 + tid];
        }
        const size_t ob = ((size_t)(slot0 + tid)) * 6 + (size_t)ch * 3;
        pbuf[ob]     = P;
        pbuf[ob + 1] = N;
        pbuf[ob + 2] = S;
    }
}

// ---------------- K3: combine halves + softplus + deterministic sum ------
__global__ __launch_bounds__(1024) void kg_reduce(const int* __restrict__ perm,
                                                  const float* __restrict__ pbuf,
                                                  float* __restrict__ out) {
    __shared__ float s[1024];
    const int t = threadIdx.x;
    float acc = 0.f;
    for (int i = t; i < KG_BPAD; i += 1024) {
        if (perm[i] >= 0) {
            const float* pb = pbuf + (size_t)i * 6;
            const float ps = pb[0] + pb[3];
            const float ns = pb[1] + pb[4];
            const float sq = pb[2] + pb[5];
            const float x  = ps - ns;
            acc += fmaxf(x, 0.f) + log1pf(expf(-fabsf(x))) + 5e-6f * sq;
        }
    }
    s[t] = acc;
    __syncthreads();
    for (int off = 512; off > 0; off >>= 1) {
        if (t < off) s[t] += s[t + off];
        __syncthreads();
    }
    if (t == 0) out[0] = s[0] * (1.0f / (float)KG_B);
}

extern "C" void kernel_launch(void* const* d_in, const int* in_sizes, int n_in,
                              void* d_out, int out_size, void* d_ws, size_t ws_size,
                              hipStream_t stream) {
    const float* ent = (const float*)d_in[0];
    const float* rel = (const float*)d_in[1];
    const float* M   = (const float*)d_in[2];
    const int*   h   = (const int*)d_in[3];
    const int*   r   = (const int*)d_in[4];
    const int*   pt  = (const int*)d_in[5];
    const int*   nt  = (const int*)d_in[6];

    int*   perm = (int*)d_ws;
    float* pbuf = (float*)d_ws + KG_BPAD;
    float* out  = (float*)d_out;

    kg_sort  <<<1, 1024, 0, stream>>>(r, perm);
    kg_main  <<<KG_NBLK, 256, 0, stream>>>(ent, rel, M, h, r, pt, nt, perm, pbuf);
    kg_reduce<<<1, 1024, 0, stream>>>(perm, pbuf, out);
}

// Round 4
// 35.283 us; speedup vs baseline: 4.7580x; 2.7082x over previous
//
#include <hip/hip_runtime.h>
#include <math.h>

#define KG_B    16384
#define KG_D    128
#define KG_NR   24
#define KG_TM   32                        // elements per block (padded segment quantum)
#define KG_BPAD (KG_B + KG_NR * KG_TM)    // 17152
#define KG_NGRP (KG_BPAD / KG_TM)         // 536

// ws ints: perm[BPAD] | cnt[24] | cur[24] | pbase[24] ; floats: partials[64] | terms[BPAD]
#define WS_CNT   KG_BPAD
#define WS_CUR   (KG_BPAD + 24)
#define WS_PBASE (KG_BPAD + 48)
#define WS_FLT   (KG_BPAD + 72)
#define WS_PART  WS_FLT
#define WS_TERMS (WS_FLT + 64)

typedef __attribute__((ext_vector_type(8))) short bf16x8;
typedef __attribute__((ext_vector_type(4))) float f32x4;

__device__ __forceinline__ unsigned bf16r(float f) {
    return (__float_as_uint(f) + 0x8000u) >> 16;
}
__device__ __forceinline__ unsigned pack2(float lo, float hi) {
    return bf16r(lo) | (bf16r(hi) << 16);
}

// ---- K0: perm = -1 everywhere, zero the 48 counters ----
__global__ __launch_bounds__(256) void kg_init(int* wsi) {
    const int i = blockIdx.x * 256 + threadIdx.x;
    if (i < KG_BPAD) wsi[i] = -1;
    if (blockIdx.x == 0 && threadIdx.x < 48) wsi[WS_CNT + threadIdx.x] = 0;
}

// ---- K1: parallel histogram (LDS per block, 24 global atomics/block) ----
__global__ __launch_bounds__(1024) void kg_hist(const int* __restrict__ r, int* wsi) {
    __shared__ int hc[24];
    const int t = threadIdx.x;
    if (t < 24) hc[t] = 0;
    __syncthreads();
    atomicAdd(&hc[r[blockIdx.x * 1024 + t]], 1);
    __syncthreads();
    if (t < 24 && hc[t] > 0) atomicAdd(&wsi[WS_CNT + t], hc[t]);
}

// ---- K2: padded exclusive scan over 24 bins ----
__global__ void kg_scan(int* wsi) {
    int run = 0;
    for (int k = 0; k < KG_NR; ++k) {
        wsi[WS_PBASE + k] = run;
        run += (wsi[WS_CNT + k] + KG_TM - 1) & ~(KG_TM - 1);
    }
}

// ---- K3: parallel scatter (per-block LDS ranks + one global claim/bin) ----
__global__ __launch_bounds__(1024) void kg_scatter(const int* __restrict__ r, int* wsi) {
    __shared__ int hc[24], hb[24];
    const int t = threadIdx.x;
    if (t < 24) hc[t] = 0;
    __syncthreads();
    const int i = blockIdx.x * 1024 + t;
    const int k = r[i];
    const int rank = atomicAdd(&hc[k], 1);
    __syncthreads();
    if (t < 24 && hc[t] > 0)
        hb[t] = wsi[WS_PBASE + t] + atomicAdd(&wsi[WS_CUR + t], hc[t]);
    __syncthreads();
    wsi[hb[k] + rank] = i;
}

// ---- K4: MFMA main. Block = 32 same-relation elements, 4 waves:
//      wave w -> rows (w&1)*16, cols (w>>1)*64. ----
__global__ __launch_bounds__(256, 2) void kg_main(
    const float* __restrict__ ent, const float* __restrict__ rel,
    const float* __restrict__ M,   const int* __restrict__ h,
    const int* __restrict__ r,     const int* __restrict__ pt,
    const int* __restrict__ nt,    const int* __restrict__ perm,
    float* __restrict__ terms)
{
    __shared__ unsigned short sX[3 * KG_TM * KG_D];   // 24 KB bf16, row-XOR-swizzled
    __shared__ unsigned short sW[KG_D * KG_D];        // 32 KB bf16 W^T, col-XOR-swizzled
    __shared__ float sScr[2][KG_TM][4];               // 1 KB score partials

    const int tid   = threadIdx.x;
    const int slot0 = blockIdx.x * KG_TM;
    const int p0    = perm[slot0];
    if (p0 < 0) {                          // fully padded / unused trailing group
        if (tid < KG_TM) terms[slot0 + tid] = 0.f;
        return;
    }
    const int rb = __builtin_amdgcn_readfirstlane(r[p0]);

    // ---- stage X: thread t -> row g=t>>3, 16 dims at e0=(t&7)*16, 3 products ----
    {
        const int g  = tid >> 3;
        const int e0 = (tid & 7) * 16;
        const int pg = perm[slot0 + g];
        const int bb = pg < 0 ? p0 : pg;
        const int idx3[3] = { h[bb], pt[bb], nt[bb] };
        const int sw = (g & 7) << 3;
#pragma unroll
        for (int t3 = 0; t3 < 3; ++t3) {
            const float* src = ent + (size_t)idx3[t3] * KG_D + e0;
            const float4 f0 = ((const float4*)src)[0];
            const float4 f1 = ((const float4*)src)[1];
            const float4 f2 = ((const float4*)src)[2];
            const float4 f3 = ((const float4*)src)[3];
            uint4 u0, u1;
            u0.x = pack2(f0.x, f0.y); u0.y = pack2(f0.z, f0.w);
            u0.z = pack2(f1.x, f1.y); u0.w = pack2(f1.z, f1.w);
            u1.x = pack2(f2.x, f2.y); u1.y = pack2(f2.z, f2.w);
            u1.z = pack2(f3.x, f3.y); u1.w = pack2(f3.z, f3.w);
            unsigned short* base = sX + t3 * (KG_TM * KG_D) + g * KG_D;
            *(uint4*)(base + ((e0    ) ^ sw)) = u0;
            *(uint4*)(base + ((e0 + 8) ^ sw)) = u1;
        }
    }
    // ---- stage W^T: thread t -> W row e=t>>1, cols (t&1)*64 .. +63 ----
    {
        const int e  = tid >> 1;
        const int c0 = (tid & 1) * 64;
        const float* src = M + ((size_t)rb << 14) + (size_t)e * KG_D + c0;
#pragma unroll
        for (int i4 = 0; i4 < 16; ++i4) {
            const float4 w4 = ((const float4*)src)[i4];
            const int cb = c0 + i4 * 4;
            sW[(cb + 0) * KG_D + (e ^ (((cb + 0) & 7) << 3))] = (unsigned short)bf16r(w4.x);
            sW[(cb + 1) * KG_D + (e ^ (((cb + 1) & 7) << 3))] = (unsigned short)bf16r(w4.y);
            sW[(cb + 2) * KG_D + (e ^ (((cb + 2) & 7) << 3))] = (unsigned short)bf16r(w4.z);
            sW[(cb + 3) * KG_D + (e ^ (((cb + 3) & 7) << 3))] = (unsigned short)bf16r(w4.w);
        }
    }
    __syncthreads();

    const int l   = tid & 63;
    const int w   = tid >> 6;
    const int rt  = w & 1;                 // row-tile (16 rows)
    const int chs = w >> 1;                // column half (64 cols)
    const int li  = l & 15;
    const int kq  = l >> 4;

    const int ar  = rt * 16 + li;          // A row = element index in block
    const int asw = (ar & 7) << 3;

    f32x4 acc[3][4];
#pragma unroll
    for (int t3 = 0; t3 < 3; ++t3)
#pragma unroll
        for (int n = 0; n < 4; ++n) acc[t3][n] = (f32x4)0.f;

#pragma unroll
    for (int kk = 0; kk < 4; ++kk) {       // K chunks of 32
        const int e0 = kk * 32 + kq * 8;
        bf16x8 af[3];
#pragma unroll
        for (int t3 = 0; t3 < 3; ++t3)
            af[t3] = *(const bf16x8*)&sX[t3 * (KG_TM * KG_D) + ar * KG_D + (e0 ^ asw)];
#pragma unroll
        for (int n = 0; n < 4; ++n) {
            const int col = chs * 64 + n * 16 + li;
            const bf16x8 bfr = *(const bf16x8*)&sW[col * KG_D + (e0 ^ ((col & 7) << 3))];
            acc[0][n] = __builtin_amdgcn_mfma_f32_16x16x32_bf16(af[0], bfr, acc[0][n], 0, 0, 0);
            acc[1][n] = __builtin_amdgcn_mfma_f32_16x16x32_bf16(af[1], bfr, acc[1][n], 0, 0, 0);
            acc[2][n] = __builtin_amdgcn_mfma_f32_16x16x32_bf16(af[2], bfr, acc[2][n], 0, 0, 0);
        }
    }

    // ---- epilogue: C/D layout col=lane&15, row=(lane>>4)*4+reg ----
    float ps[4] = {0,0,0,0}, ns[4] = {0,0,0,0}, sq[4] = {0,0,0,0};
    const float* relrow = rel + (size_t)rb * KG_D + chs * 64;
#pragma unroll
    for (int n = 0; n < 4; ++n) {
        const float rv = relrow[n * 16 + li];
#pragma unroll
        for (int j = 0; j < 4; ++j) {
            const float va = acc[0][n][j];
            const float vp = acc[1][n][j];
            const float vn = acc[2][n][j];
            const float s  = va + rv;
            const float dp = s - vp;
            const float dn = s - vn;
            ps[j] += dp * dp;
            ns[j] += dn * dn;
            sq[j] += va * va + vp * vp + vn * vn + rv * rv;
        }
    }
#pragma unroll
    for (int j = 0; j < 4; ++j)
#pragma unroll
        for (int m = 1; m < 16; m <<= 1) {
            ps[j] += __shfl_xor(ps[j], m);
            ns[j] += __shfl_xor(ns[j], m);
            sq[j] += __shfl_xor(sq[j], m);
        }

    if (li == 0) {
#pragma unroll
        for (int j = 0; j < 4; ++j) {
            const int row = rt * 16 + kq * 4 + j;
            sScr[chs][row][0] = ps[j];
            sScr[chs][row][1] = ns[j];
            sScr[chs][row][2] = sq[j];
        }
    }
    __syncthreads();

    if (tid < KG_TM) {
        const int row = tid;
        const float P = sScr[0][row][0] + sScr[1][row][0];
        const float N = sScr[0][row][1] + sScr[1][row][1];
        const float S = sScr[0][row][2] + sScr[1][row][2];
        const int pg = perm[slot0 + row];
        float term = 0.f;
        if (pg >= 0) {
            const float x = P - N;                              // pos - neg
            term = fmaxf(x, 0.f) + log1pf(expf(-fabsf(x)))      // softplus
                 + 5e-6f * S;                                   // lambda/2 * l2
        }
        terms[slot0 + row] = term;
    }
}

// ---- K5/K6: deterministic two-stage reduction ----
__global__ __launch_bounds__(256) void kg_reduce1(const float* __restrict__ terms,
                                                  float* __restrict__ partials) {
    __shared__ float s[256];
    const int t = threadIdx.x;
    float acc = 0.f;
    for (int i = blockIdx.x * 256 + t; i < KG_BPAD; i += 64 * 256) acc += terms[i];
    s[t] = acc;
    __syncthreads();
    for (int off = 128; off > 0; off >>= 1) {
        if (t < off) s[t] += s[t + off];
        __syncthreads();
    }
    if (t == 0) partials[blockIdx.x] = s[0];
}

__global__ __launch_bounds__(64) void kg_reduce2(const float* __restrict__ partials,
                                                 float* __restrict__ out) {
    float v = partials[threadIdx.x];
    for (int off = 32; off > 0; off >>= 1) v += __shfl_down(v, off);
    if (threadIdx.x == 0) out[0] = v * (1.0f / (float)KG_B);
}

extern "C" void kernel_launch(void* const* d_in, const int* in_sizes, int n_in,
                              void* d_out, int out_size, void* d_ws, size_t ws_size,
                              hipStream_t stream) {
    const float* ent = (const float*)d_in[0];
    const float* rel = (const float*)d_in[1];
    const float* M   = (const float*)d_in[2];
    const int*   h   = (const int*)d_in[3];
    const int*   r   = (const int*)d_in[4];
    const int*   pt  = (const int*)d_in[5];
    const int*   nt  = (const int*)d_in[6];

    int*   wsi      = (int*)d_ws;
    float* partials = (float*)d_ws + WS_PART;
    float* terms    = (float*)d_ws + WS_TERMS;
    float* out      = (float*)d_out;

    kg_init   <<<(KG_BPAD + 255) / 256, 256, 0, stream>>>(wsi);
    kg_hist   <<<KG_B / 1024, 1024, 0, stream>>>(r, wsi);
    kg_scan   <<<1, 1, 0, stream>>>(wsi);
    kg_scatter<<<KG_B / 1024, 1024, 0, stream>>>(r, wsi);
    kg_main   <<<KG_NGRP, 256, 0, stream>>>(ent, rel, M, h, r, pt, nt, wsi, terms);
    kg_reduce1<<<64, 256, 0, stream>>>(terms, partials);
    kg_reduce2<<<1, 64, 0, stream>>>(partials, out);
}